// Round 10
// baseline (375.250 us; speedup 1.0000x reference)
//
#include <hip/hip_runtime.h>

// MN neuron forward sim: T=1000 sequential steps, 64x512 independent chains.
// Round 10: ILP-4 — 4 independent chains per consumer lane on the R7b skeleton.
// Evidence trail: R9 speculation FAILED (90us; chain audit shows the carried
// path through spike-reset sources i1r/i2r/tm_ was never shortened; +19
// instr/step cost only ~1.7cyc each). The only per-chain win so far was R6's
// ILP-2 (138 vs 183 cyc/chain-step despite bad structure) -> the loop is
// LATENCY-bound on its ~13-edge carried chain (~183 cyc), with ~2.8x issue
// headroom. ILP-4: four chains' steps are independent; compiler interleaves;
// expect ~max(4x~58 issue, ~190 latency) ~= 230-260 cyc per 4 chain-steps.
//   - consumer wave: chains (lane, lane+64, lane+128, lane+192); state and
//     params in 4-arrays indexed ONLY from fully-unrolled loops (static
//     indices; runtime-indexed arrays go to scratch).
//   - block = 256 chains -> 128 blocks x 128 threads (idle CUs irrelevant:
//     wall time = one wave's serial step time).
//   - producer wave: global_load_lds w=16, 1 row (1KB) per issue, 20/chunk;
//     spike flush ds_read_b128 -> NT dwordx4, 20 rows/chunk. Verbatim R7b
//     scheme otherwise (vmcnt(0)+lgkmcnt(0) before each barrier).
//   - raw s_barrier, SGPR-pinned constants, s_setprio 1: proven pieces.
// CORRECTNESS: binary spike output => bit-exact f32 vs numpy ref:
//   mn_step is the byte-identical verified function (exact ref op order, no
//   FMA contraction, selects for resets); chains fully independent.
// Barrier ledger: producer B0 + 50 = 51; consumer B0 + 50 = 51. Double
// buffer: producer fills xb[(c+1)&1] while consumer computes on xb[c&1];
// consumer's lgkmcnt(0) before B(c+1) retires all its ds reads/writes before
// the producer may overwrite xb or flush sb. flush(49) runs after the final
// barrier (consumer exited; its sb writes retired before B50).

#define T_STEPS 1000
#define B_DIM 64
#define N_DIM 512
#define BN (B_DIM * N_DIM)   // 32768

#define K_CHUNK 20
#define NCHUNK (T_STEPS / K_CHUNK)   // 50
#define CPB 256                      // chains per block (4 per lane)

typedef const __attribute__((address_space(1))) void* gp_t;
typedef __attribute__((address_space(3))) void* lp_t;
typedef float f32x4 __attribute__((ext_vector_type(4)));

__device__ __forceinline__ void raw_barrier() {
    asm volatile("s_barrier" ::: "memory");
}

struct Consts {
    float k200, k20, kDT, kEL, kG, kTINF, kB, kR1, kR2, kTR;
};

__device__ __forceinline__ float mn_step(float xt, float lin, float av,
                                         float A1v, float A2v, const Consts& K,
                                         float& V, float& i1, float& i2,
                                         float& Thr)
{
#pragma clang fp contract(off)
    // identical IEEE op order to the verified kernel; constants in SGPRs
    i1 = i1 - (K.k200 * i1) * K.kDT;
    i2 = i2 - (K.k20  * i2) * K.kDT;
    float p  = lin * xt;
    float q  = p + i1;
    float r  = q + i2;
    float e  = V - K.kEL;
    float g  = K.kG * e;
    float s  = r - g;
    float d  = K.kDT * s;
    V = V + d;
    float e2 = V - K.kEL;
    float u  = av * e2;
    float w  = Thr - K.kTINF;
    float bw = K.kB * w;
    float s2 = u - bw;
    float d2 = K.kDT * s2;
    Thr = Thr + d2;
    float diff = V - Thr;
    bool  sb   = diff > 0.0f;
    float spk  = sb ? 1.0f : 0.0f;
    float i1r = (K.kR1 * i1) + A1v;
    float i2r = (K.kR2 * i2) + A2v;
    i1  = sb ? i1r : i1;
    i2  = sb ? i2r : i2;
    float tm = fmaxf(Thr, K.kTR);
    Thr = sb ? tm : Thr;
    V   = sb ? K.kEL : V;                   // VR == EL == -0.07f (same bits)
    return spk;
}

__global__ __launch_bounds__(128, 1) void mn_neuron_kernel(
    const float* __restrict__ x, const float* __restrict__ linear,
    const float* __restrict__ a, const float* __restrict__ A1,
    const float* __restrict__ A2, float* __restrict__ out)
{
#pragma clang fp contract(off)
    __shared__ float xb_buf[2][K_CHUNK][CPB];   // staged x      (40 KiB)
    __shared__ float sb_buf[2][K_CHUNK][CPB];   // staged spikes (40 KiB)

    const int lane = threadIdx.x & 63;
    const int wid  = threadIdx.x >> 6;     // 0 = consumer, 1 = producer
    const int blk  = blockIdx.x;

    if (wid == 1) {
        // ---- producer: x staging + spike flush ----
        // one row = CPB floats = 1024B = 64 lanes x 16B -> one w=16 issue/row
        const float* pl = x + (size_t)blk * CPB + (size_t)lane * 4;
        float* outp = out + (size_t)blk * CPB;

        auto issue = [&](int k) {   // chunk k's 20 row-loads -> xb[k&1]
            const float* pc = pl + (size_t)(k * K_CHUNK) * BN;
            float* dst = &xb_buf[k & 1][0][0];
#pragma unroll
            for (int r = 0; r < K_CHUNK; ++r) {
                __builtin_amdgcn_global_load_lds(
                    (gp_t)(pc + (size_t)r * BN),
                    (lp_t)(dst + r * CPB), 16, 0, 0);
            }
        };

        auto flush = [&](int k) {   // spikes of chunk k -> HBM, 1 row/iter
            const int kb = k & 1;
#pragma unroll
            for (int r = 0; r < K_CHUNK; ++r) {
                const f32x4 v = *reinterpret_cast<const f32x4*>(
                    &sb_buf[kb][r][lane * 4]);                   // ds_read_b128
                f32x4* dp = reinterpret_cast<f32x4*>(
                    outp + (size_t)(k * K_CHUNK + r) * BN + (size_t)lane * 4);
                __builtin_nontemporal_store(v, dp);              // dwordx4 nt
            }
        };

        issue(0);
        asm volatile("s_waitcnt vmcnt(0)" ::: "memory");
        raw_barrier();                                           // B0

        for (int c = 0; c < NCHUNK; ++c) {
            if (c + 1 < NCHUNK) issue(c + 1);
            if (c >= 1)         flush(c - 1);
            asm volatile("s_waitcnt vmcnt(0) lgkmcnt(0)" ::: "memory");
            raw_barrier();                                       // B(c+1)
        }
        flush(NCHUNK - 1);   // after final barrier; consumer exited
    } else {
        // ---- consumer: 4 independent chains per lane (ILP-4) ----
        const int i0 = blk * CPB + lane;

        float lin[4], av[4], A1r[4], A2r[4];
        float V[4], i1[4], i2[4], Thr[4];

        Consts K = {200.0f, 20.0f, 0.01f, -0.07f,
                    45.24007797241211f, -0.05f, 12.77495288848877f,
                    0.3858567178249359f, -1.1421641111373901f, -0.06f};
        asm volatile("" : "+s"(K.k200), "+s"(K.k20), "+s"(K.kDT),
                          "+s"(K.kEL), "+s"(K.kG), "+s"(K.kTINF),
                          "+s"(K.kB), "+s"(K.kR1), "+s"(K.kR2), "+s"(K.kTR));

#pragma unroll
        for (int k = 0; k < 4; ++k) {
            const int n = (i0 + 64 * k) & (N_DIM - 1);
            lin[k] = linear[n];
            av[k]  = a[n];
            A1r[k] = A1[n];
            A2r[k] = A2[n];
            V[k]   = K.kEL;
            i1[k]  = 0.0f;
            i2[k]  = 0.0f;
            Thr[k] = K.kTINF;
        }

        asm volatile("s_setprio 1" ::: "memory");
        raw_barrier();                                           // B0

        for (int c = 0; c < NCHUNK; ++c) {
            const float* src = &xb_buf[c & 1][0][lane];
            float*       dst = &sb_buf[c & 1][0][lane];
            // unroll-2 keeps the body ~2KB (I-cache safe) while giving the
            // scheduler 8 independent mn_steps to interleave.
#pragma unroll 2
            for (int j = 0; j < K_CHUNK; ++j) {
#pragma unroll
                for (int k = 0; k < 4; ++k) {
                    float xt  = src[j * CPB + 64 * k];   // ds_read_b32 imm
                    float spk = mn_step(xt, lin[k], av[k], A1r[k], A2r[k], K,
                                        V[k], i1[k], i2[k], Thr[k]);
                    dst[j * CPB + 64 * k] = spk;         // ds_write_b32 imm
                }
            }
            asm volatile("s_waitcnt lgkmcnt(0)" ::: "memory");
            raw_barrier();                                       // B(c+1)
        }
    }
}

extern "C" void kernel_launch(void* const* d_in, const int* in_sizes, int n_in,
                              void* d_out, int out_size, void* d_ws, size_t ws_size,
                              hipStream_t stream) {
    const float* x      = (const float*)d_in[0];
    const float* linear = (const float*)d_in[1];
    const float* a      = (const float*)d_in[2];
    const float* A1     = (const float*)d_in[3];
    const float* A2     = (const float*)d_in[4];
    float* out = (float*)d_out;

    // 128 blocks x 128 threads (1 consumer + 1 producer wave; 4 chains/lane)
    mn_neuron_kernel<<<BN / CPB, 128, 0, stream>>>(x, linear, a, A1, A2, out);
}

// Round 11
// 254.586 us; speedup vs baseline: 1.4740x; 1.4740x over previous
//
#include <hip/hip_runtime.h>

// MN neuron forward sim: T=1000 sequential steps, 64x512 independent chains.
// Round 11: dual-path SOFTWARE-PIPELINED speculation (select-late).
// Model fitting ALL rounds: per-step ~= carried_edges x ~9cyc + issue:
//   R7b 13x9+70=187~=183; R9 (select-early spec) 16 edges -> 216 ✓ (it
//   LENGTHENED the chain); R6 2x117+40~=277 ✓; R10 partial-interleave 520 ✓.
// Fix vs R9: carry the candidate PAIR {V',Thr',i1,i2,cmp}x{ns,sp} across
// iterations. Body t: resolve sb_t from PREVIOUS pair's cmp-bits (mask ops,
// 2 edges); cnd-select true state (1 edge); compute resets; dual-integrate
// step t+1 on both hypotheses (needs NO sb -> overlaps this body's issue
// stream instead of sitting inside the resolve cycle). The 13-edge integrate
// is consumed one full body (~105 issue cyc) later.
// sb via DIRECT compare-pair (Vp > Tp): bit-equal to (Vp-Tp)>0 — f32 sub of
// distinct floats never rounds to 0 when denormals are preserved, and these
// dynamics (|V|,|Thr| ~ 1e-2, steps ~1e-4) never produce subnormal diffs.
// Dual-path exact folds e_s=+0, g_s=+0, s_s=r_s: verbatim from R9 which
// PASSED bit-exact (absmax 0.0) — only the schedule changes here.
// Producer: R8's verified quad-buffer 2-chunks-resident scheme (consumer's
// last body prefetches next chunk's row 0 BEFORE the barrier).
// CORRECTNESS: every reference op is applied to the cnd-selected input via
// select(sb,f(a),f(b)) == f(select(sb,a,b)) with identical ops per branch;
// binary spike output must stay bit-exact (absmax 0.0).
// Barrier ledger: producer B0+50=51; consumer B0+50=51. Buffer safety:
// producer issues chunk c+3 into buf[(c-1)&3] after B(c); consumer's last
// touch of buf[c-1] was in chunk c-1, retired via lgkmcnt(0) before B(c).
// Consumer reads buf[c+1] row 0 during chunk c: producer guaranteed chunk
// c+1 resident before B(c) (vmcnt(5) with 2 chunks in flight). Last chunk's
// tail integrate reads stale buf[2] row 0 (in-bounds, discarded).

#define T_STEPS 1000
#define B_DIM 64
#define N_DIM 512
#define BN (B_DIM * N_DIM)   // 32768

#define K_CHUNK 20
#define NCHUNK (T_STEPS / K_CHUNK)   // 50
#define NBUF 4

typedef const __attribute__((address_space(1))) void* gp_t;
typedef __attribute__((address_space(3))) void* lp_t;
typedef float f32x4 __attribute__((ext_vector_type(4)));

__device__ __forceinline__ void raw_barrier() {
    asm volatile("s_barrier" ::: "memory");
}

struct Consts {
    float k200, k20, kDT, kEL, kG, kTINF, kB, kR1, kR2, kTR;
};

struct Pairs {
    float Vn, Vs;     // V' candidates (post-integration, pre-reset)
    float Tn, Ts;     // Thr' candidates
    float i1n, i1s;   // i1 post-decay pre-reset candidates
    float i2n, i2s;
    bool  cn, cs;     // spike-compare candidates (V' > Thr')
};

// Dual-path integrate of ONE step. n-inputs = state if prev step didn't
// spike; s-inputs = reset state (V=VR fixed). Reference op order per path.
__device__ __forceinline__ Pairs dual_integrate(
    float xt, float lin, float av, const Consts& K,
    float Vin, float i1nin, float i2nin, float Tnin,
    float i1sin, float i2sin, float Tsin)
{
#pragma clang fp contract(off)
    Pairs P;
    float p   = lin * xt;                       // shared: identical op+inputs
    // ---- no-spike path (exact reference ops) ----
    float a1n = i1nin - (K.k200 * i1nin) * K.kDT;
    float a2n = i2nin - (K.k20  * i2nin) * K.kDT;
    float qn  = p + a1n;
    float rn  = qn + a2n;
    float en  = Vin - K.kEL;
    float gn  = K.kG * en;
    float sn  = rn - gn;
    float dn  = K.kDT * sn;
    float Vpn = Vin + dn;
    float e2n = Vpn - K.kEL;
    float un  = av * e2n;
    float wn  = Tnin - K.kTINF;
    float bwn = K.kB * wn;
    float s2n = un - bwn;
    float d2n = K.kDT * s2n;
    float Tpn = Tnin + d2n;
    // ---- spike path: V=VR; exact folds e=+0, g=+0, s=r (R9-verified) ----
    float a1s = i1sin - (K.k200 * i1sin) * K.kDT;
    float a2s = i2sin - (K.k20  * i2sin) * K.kDT;
    float qs  = p + a1s;
    float rs  = qs + a2s;
    float ds  = K.kDT * rs;
    float Vps = K.kEL + ds;                     // VR == EL (same bits)
    float e2s = Vps - K.kEL;
    float us  = av * e2s;
    float ws  = Tsin - K.kTINF;
    float bws = K.kB * ws;
    float s2s = us - bws;
    float d2s = K.kDT * s2s;
    float Tps = Tsin + d2s;
    P.Vn = Vpn; P.Vs = Vps; P.Tn = Tpn; P.Ts = Tps;
    P.i1n = a1n; P.i1s = a1s; P.i2n = a2n; P.i2s = a2s;
    P.cn = Vpn > Tpn;                           // == (Vpn-Tpn) > 0 (see notes)
    P.cs = Vps > Tps;
    return P;
}

// Resolve step t from carried pairs, then dual-integrate step t+1.
__device__ __forceinline__ float resolve_and_advance(
    float xt1, float lin, float av, float A1v, float A2v, const Consts& K,
    Pairs& P, bool& sbp)
{
#pragma clang fp contract(off)
    // step t's spike decision: mask-select of precomputed compare bits
    bool  sb  = sbp ? P.cs : P.cn;              // SALU mask ops
    float spk = sb ? 1.0f : 0.0f;
    // true post-integration (pre-reset) state of step t
    float V1  = sbp ? P.Vs  : P.Vn;
    float T1  = sbp ? P.Ts  : P.Tn;
    float i1d = sbp ? P.i1s : P.i1n;
    float i2d = sbp ? P.i2s : P.i2n;
    // reset values from true state (exact reference ops)
    float i1r  = (K.kR1 * i1d) + A1v;
    float i2r  = (K.kR2 * i2d) + A2v;
    float tmax = fmaxf(T1, K.kTR);
    // dual-integrate step t+1: hypotheses branch on sb (resolved NEXT body)
    P = dual_integrate(xt1, lin, av, K,
                       V1, i1d, i2d, T1,        // sb_t = 0 hypothesis
                       i1r, i2r, tmax);         // sb_t = 1 hypothesis (V=VR)
    sbp = sb;
    return spk;
}

__global__ __launch_bounds__(128, 1) void mn_neuron_kernel(
    const float* __restrict__ x, const float* __restrict__ linear,
    const float* __restrict__ a, const float* __restrict__ A1,
    const float* __restrict__ A2, float* __restrict__ out)
{
#pragma clang fp contract(off)
    __shared__ float xb_buf[NBUF][K_CHUNK][64];   // staged x (quad buffer)
    __shared__ float sb_buf[2][K_CHUNK][64];      // staged spikes

    const int lane = threadIdx.x & 63;
    const int wid  = threadIdx.x >> 6;     // 0 = consumer, 1 = producer
    const int blk  = blockIdx.x;

    if (wid == 1) {
        // ---- producer: verbatim R8 (verified) ----
        const float* pl = x + (size_t)(lane >> 4) * BN
                            + (size_t)blk * 64 + (size_t)(lane & 15) * 4;
        float* outp = out + (size_t)blk * 64;

        auto issue = [&](int k) {   // chunk k's 5 width-16 loads -> xb[k&3]
            const float* pc = pl + (size_t)(k * K_CHUNK) * BN;
            float* dst = &xb_buf[k & (NBUF - 1)][0][0];
#pragma unroll
            for (int s5 = 0; s5 < K_CHUNK / 4; ++s5) {
                __builtin_amdgcn_global_load_lds(
                    (gp_t)(pc + (size_t)(s5 * 4) * BN),
                    (lp_t)(dst + s5 * 4 * 64), 16, 0, 0);
            }
        };

        const int r0 = lane >> 4;          // 0..3
        const int c4 = (lane & 15) * 4;    // 0,4,..,60
        auto flush = [&](int k) {          // spikes of chunk k -> HBM
            const int kb = k & 1;
#pragma unroll
            for (int pz = 0; pz < K_CHUNK / 4; ++pz) {
                const int row = pz * 4 + r0;
                const f32x4 v = *reinterpret_cast<const f32x4*>(
                    &sb_buf[kb][row][c4]);                       // ds_read_b128
                f32x4* dp = reinterpret_cast<f32x4*>(
                    outp + (size_t)(k * K_CHUNK + row) * BN + c4);
                __builtin_nontemporal_store(v, dp);              // dwordx4 nt
            }
        };

        issue(0); issue(1); issue(2);                            // 15 out
        asm volatile("s_waitcnt vmcnt(5)" ::: "memory");         // 0,1 resident
        raw_barrier();                                           // B0

        for (int c = 0; c < NCHUNK; ++c) {
            if (c + 3 < NCHUNK) issue(c + 3);
            if (c <= NCHUNK - 4) {
                asm volatile("s_waitcnt vmcnt(5)" ::: "memory"); // c+2 resident
            } else {
                asm volatile("s_waitcnt vmcnt(0)" ::: "memory");
            }
            if (c >= 1) flush(c - 1);
            asm volatile("s_waitcnt lgkmcnt(0)" ::: "memory");   // sb reusable
            raw_barrier();                                       // B(c+1)
        }
        flush(NCHUNK - 1);   // after final barrier; consumer exited
    } else {
        // ---- consumer: pipelined dual-path recurrence ----
        const int idx = blk * 64 + lane;       // b*N + n
        const int n   = idx & (N_DIM - 1);

        const float lin = linear[n];
        const float av  = a[n];
        const float A1v = A1[n];
        const float A2v = A2[n];

        Consts K = {200.0f, 20.0f, 0.01f, -0.07f,
                    45.24007797241211f, -0.05f, 12.77495288848877f,
                    0.3858567178249359f, -1.1421641111373901f, -0.06f};
        asm volatile("" : "+s"(K.k200), "+s"(K.k20), "+s"(K.kDT),
                          "+s"(K.kEL), "+s"(K.kG), "+s"(K.kTINF),
                          "+s"(K.kB), "+s"(K.kR1), "+s"(K.kR2), "+s"(K.kTR));

        asm volatile("s_setprio 1" ::: "memory");
        raw_barrier();                                           // B0

        // prologue: integrate step 0 from ref init (fictional sb_{-1}=false).
        // n-inputs = init; s-inputs duplicate init i/Thr (discarded: sbp=0).
        // n-path reproduces ref step 0 exactly: a1n = 0-(200*0)*DT = +0,
        // qn = p + +0 == ref's q (identical op on identical bits).
        bool  sbp = false;
        Pairs P;
        {
            float x0 = xb_buf[0][0][lane];
            P = dual_integrate(x0, lin, av, K,
                               K.kEL, 0.0f, 0.0f, K.kTINF,
                               0.0f, 0.0f, K.kTINF);
        }

        for (int c = 0; c < NCHUNK; ++c) {
            const float* src = &xb_buf[c & (NBUF - 1)][0][lane];
            const float* nxt = &xb_buf[(c + 1) & (NBUF - 1)][0][lane];
            float*       dst = &sb_buf[c & 1][0][lane];
#pragma unroll
            for (int j = 0; j < K_CHUNK; ++j) {
                // x for step t+1: row j+1, or next chunk's row 0 (resident:
                // producer keeps 2 chunks ahead). Last chunk's tail reads
                // stale buf[2] row 0 -> in-bounds, result discarded.
                float xt1 = (j < K_CHUNK - 1) ? src[(j + 1) * 64] : nxt[0];
                float spk = resolve_and_advance(xt1, lin, av, A1v, A2v, K,
                                                P, sbp);
                dst[j * 64] = spk;                   // ds_write_b32 imm
            }
            asm volatile("s_waitcnt lgkmcnt(0)" ::: "memory");
            raw_barrier();                                       // B(c+1)
        }
    }
}

extern "C" void kernel_launch(void* const* d_in, const int* in_sizes, int n_in,
                              void* d_out, int out_size, void* d_ws, size_t ws_size,
                              hipStream_t stream) {
    const float* x      = (const float*)d_in[0];
    const float* linear = (const float*)d_in[1];
    const float* a      = (const float*)d_in[2];
    const float* A1     = (const float*)d_in[3];
    const float* A2     = (const float*)d_in[4];
    float* out = (float*)d_out;

    // 512 blocks x 128 threads (1 consumer wave + 1 producer wave each)
    mn_neuron_kernel<<<BN / 64, 128, 0, stream>>>(x, linear, a, A1, A2, out);
}

// Round 12
// 232.835 us; speedup vs baseline: 1.6117x; 1.0934x over previous
//
#include <hip/hip_runtime.h>

// MN neuron forward sim: T=1000 sequential steps, 64x512 independent chains.
// Round 12: surgical carried-chain cut 16 -> 12 edges on the R7b skeleton.
// Cross-round model: per-step ~= chain_edges x ~11.4 cyc (R7b: 16 x 11.4 =
// 183 ✓); off-chain ops cost ~2 cyc marginal (R7b -3 ops = -6 cyc; R9 +19
// ops = +33 cyc). True R7b critical cycle runs through i1: sel(i1) ->
// decay(3) -> q -> r -> s -> d -> V' -> e2 -> u -> s2 -> d2 -> Thr' -> diff
// -> cmp -> sel = 16 edges. Cut to 12:
//  1. PARALLEL-DECAY (select-late, i-path only): during step t compute
//     decay(i12_dec) AND decay(i12_reset) for step t+1 (off-chain: depend
//     only on this step's i12), select AFTER decay when sb_t resolves.
//     decay(select(b,x,y)) == select(b,decay(x),decay(y)) bit-exact
//     (identical ops per branch -- R9/R11-proven machinery, both passed).
//  2. e-carry: e_{t+1} = sb ? +0.0f : e2 (VR-EL = +0.0f exact, R9-proven;
//     e2 = V'-EL is the identical ref op already computed).
//  3. direct compare sb = (V' > Thr') == (diff > 0) bit-exact with denormals
//     preserved (R11 used exactly this; absmax 0.0).
// New cycle: cmp->sel(i12)->q->r->s->d->V'->e2->u->s2->d2->T'->cmp = 12.
// Decay/reset candidates packed as float2 (i1,i2) pairs -> v_pk_{mul,add,sub}
// _f32 (per-half IEEE == scalar); they run in the latency shadow.
// CORRECTNESS: every reference op applied to the selected input in reference
// order; binary spike output must stay bit-exact (absmax 0.0).
// Producer wave, barriers, staging, SGPR consts, LDS spike staging + NT
// flush: verbatim from verified R7b (~76.5us best).

#define T_STEPS 1000
#define B_DIM 64
#define N_DIM 512
#define BN (B_DIM * N_DIM)   // 32768

#define K_CHUNK 20
#define NCHUNK (T_STEPS / K_CHUNK)   // 50

typedef const __attribute__((address_space(1))) void* gp_t;
typedef __attribute__((address_space(3))) void* lp_t;
typedef float f32x4 __attribute__((ext_vector_type(4)));
typedef float f32x2 __attribute__((ext_vector_type(2)));

__device__ __forceinline__ void raw_barrier() {
    asm volatile("s_barrier" ::: "memory");
}

struct Consts {
    float k200, k20, kDT, kEL, kG, kTINF, kB, kR1, kR2, kTR;
};

__global__ __launch_bounds__(128, 1) void mn_neuron_kernel(
    const float* __restrict__ x, const float* __restrict__ linear,
    const float* __restrict__ a, const float* __restrict__ A1,
    const float* __restrict__ A2, float* __restrict__ out)
{
#pragma clang fp contract(off)
    __shared__ float xb_buf[2][K_CHUNK][64];   // staged x
    __shared__ float sb_buf[2][K_CHUNK][64];   // staged spikes

    const int lane = threadIdx.x & 63;
    const int wid  = threadIdx.x >> 6;     // 0 = consumer, 1 = producer
    const int blk  = blockIdx.x;

    if (wid == 1) {
        // ---- producer: x staging + spike flush (verbatim R7b) ----
        const float* pl = x + (size_t)(lane >> 4) * BN
                            + (size_t)blk * 64 + (size_t)(lane & 15) * 4;
        float* outp = out + (size_t)blk * 64;

        auto issue = [&](int k) {   // chunk k's 5 width-16 loads -> xb[k&1]
            const float* pc = pl + (size_t)(k * K_CHUNK) * BN;
            float* dst = &xb_buf[k & 1][0][0];
#pragma unroll
            for (int s5 = 0; s5 < K_CHUNK / 4; ++s5) {
                __builtin_amdgcn_global_load_lds(
                    (gp_t)(pc + (size_t)(s5 * 4) * BN),
                    (lp_t)(dst + s5 * 4 * 64), 16, 0, 0);
            }
        };

        const int r0 = lane >> 4;          // 0..3
        const int c4 = (lane & 15) * 4;    // 0,4,..,60
        auto flush = [&](int k) {          // spikes of chunk k -> HBM
            const int kb = k & 1;
#pragma unroll
            for (int pz = 0; pz < K_CHUNK / 4; ++pz) {
                const int row = pz * 4 + r0;
                const f32x4 v = *reinterpret_cast<const f32x4*>(
                    &sb_buf[kb][row][c4]);                       // ds_read_b128
                f32x4* dp = reinterpret_cast<f32x4*>(
                    outp + (size_t)(k * K_CHUNK + row) * BN + c4);
                __builtin_nontemporal_store(v, dp);              // dwordx4 nt
            }
        };

        issue(0);
        asm volatile("s_waitcnt vmcnt(0)" ::: "memory");
        raw_barrier();                                           // B0

        for (int c = 0; c < NCHUNK; ++c) {
            if (c + 1 < NCHUNK) issue(c + 1);
            if (c >= 1)         flush(c - 1);
            asm volatile("s_waitcnt vmcnt(0) lgkmcnt(0)" ::: "memory");
            raw_barrier();                                       // B(c+1)
        }
        flush(NCHUNK - 1);   // after final barrier; consumer exited
    } else {
        // ---- consumer: 12-edge-chain recurrence ----
        const int idx = blk * 64 + lane;       // b*N + n
        const int n   = idx & (N_DIM - 1);

        const float lin = linear[n];
        const float av  = a[n];
        const float A1v = A1[n];
        const float A2v = A2[n];

        Consts K = {200.0f, 20.0f, 0.01f, -0.07f,
                    45.24007797241211f, -0.05f, 12.77495288848877f,
                    0.3858567178249359f, -1.1421641111373901f, -0.06f};
        asm volatile("" : "+s"(K.k200), "+s"(K.k20), "+s"(K.kDT),
                          "+s"(K.kEL), "+s"(K.kG), "+s"(K.kTINF),
                          "+s"(K.kB), "+s"(K.kR1), "+s"(K.kR2), "+s"(K.kTR));

        // packed-constant pairs for the pk islands (VGPR/SGPR pairs; VOP3P
        // cannot take literals). Per-half ops are IEEE == scalar ops.
        const f32x2 K12 = {200.0f, 20.0f};
        const f32x2 DT2 = {0.01f, 0.01f};
        const f32x2 R12 = {0.3858567178249359f, -1.1421641111373901f};
        const f32x2 A12 = {A1v, A2v};

        // ---- carried state (prologue = reference init, fictional sb_{-1}=0)
        bool  sbp = false;
        f32x2 z2  = {0.0f, 0.0f};
        // dn2 = decay({0,0}) via the exact ref ops: 0 - (K*0)*DT = +0.0
        f32x2 dn2 = z2 - (K12 * z2) * DT2;   // no-spike decay candidates
        f32x2 ds2 = dn2;                     // spike candidates (unselected)
        float e2p = 0.0f;    // ref step0 e = EL-EL = +0.0f exactly
        float Vpp = K.kEL;   // V entering step 0
        float Tpp = K.kTINF; // Thr entering step 0
        float tmp_ = K.kTINF; // spike-branch Thr source (unselected at t=0)

        asm volatile("s_setprio 1" ::: "memory");
        raw_barrier();                                           // B0

        for (int c = 0; c < NCHUNK; ++c) {
            const float* src = &xb_buf[c & 1][0][lane];
            float*       dst = &sb_buf[c & 1][0][lane];
#pragma unroll
            for (int j = 0; j < K_CHUNK; ++j) {
                float xt = src[j * 64];                  // ds_read_b32 imm

                // resolve step t state (1 cndmask each after prev cmp)
                f32x2 i12;                               // decayed, pre-reset
                i12.x = sbp ? ds2.x : dn2.x;
                i12.y = sbp ? ds2.y : dn2.y;
                float e = sbp ? 0.0f  : e2p;             // VR-EL = +0 fold
                float V = sbp ? K.kEL : Vpp;             // VR == EL bits
                float T = sbp ? tmp_  : Tpp;

                // V integration (exact ref op order)
                float p  = lin * xt;
                float q  = p + i12.x;
                float r  = q + i12.y;
                float g  = K.kG * e;
                float s  = r - g;
                float d  = K.kDT * s;
                float Vp = V + d;
                // Thr integration (exact ref op order)
                float e2 = Vp - K.kEL;
                float u  = av * e2;
                float w  = T - K.kTINF;
                float bw = K.kB * w;
                float s2 = u - bw;
                float d2 = K.kDT * s2;
                float Tp = T + d2;
                // spike decision: direct cmp == (Vp-Tp)>0 (R11-proven)
                bool sb = Vp > Tp;
                dst[j * 64] = sb ? 1.0f : 0.0f;          // ds_write_b32 imm

                // off-chain: next step's spike-branch sources + BOTH decay
                // candidates (select-late happens at next iteration's top)
                float tm = fmaxf(Tp, K.kTR);
                f32x2 i12r = (R12 * i12) + A12;          // pk_mul + pk_add
                dn2 = i12  - (K12 * i12)  * DT2;         // pk x3
                ds2 = i12r - (K12 * i12r) * DT2;         // pk x3

                e2p = e2; Vpp = Vp; Tpp = Tp; tmp_ = tm; sbp = sb;
            }
            asm volatile("s_waitcnt lgkmcnt(0)" ::: "memory");
            raw_barrier();                                       // B(c+1)
        }
    }
}

extern "C" void kernel_launch(void* const* d_in, const int* in_sizes, int n_in,
                              void* d_out, int out_size, void* d_ws, size_t ws_size,
                              hipStream_t stream) {
    const float* x      = (const float*)d_in[0];
    const float* linear = (const float*)d_in[1];
    const float* a      = (const float*)d_in[2];
    const float* A1     = (const float*)d_in[3];
    const float* A2     = (const float*)d_in[4];
    float* out = (float*)d_out;

    // 512 blocks x 128 threads (1 consumer wave + 1 producer wave each)
    mn_neuron_kernel<<<BN / 64, 128, 0, stream>>>(x, linear, a, A1, A2, out);
}